// Round 1
// baseline (143.174 us; speedup 1.0000x reference)
//
#include <hip/hip_runtime.h>

#define NND 2000
#define KNB 16
#define CS 128
#define CZ 64
#define NRBF 64
#define NE (NND*KNB)

// ---------------------------------------------------------------------------
// Kernel P: per-node gate projections G1/G2 (b_gate folded into G1) and
// per-edge kf = edge_features @ w_edge + b_edge.
// blocks [0, 500): 4 nodes each (1 wave per node)
// blocks [500, 500+8000): 4 edges each (1 wave per edge)
// ---------------------------------------------------------------------------
__global__ __launch_bounds__(256) void precompute_kernel(
    const float* __restrict__ nf, const float* __restrict__ ef,
    const float* __restrict__ w_gate, const float* __restrict__ b_gate,
    const float* __restrict__ w_edge, const float* __restrict__ b_edge,
    float* __restrict__ g1, float* __restrict__ g2, float* __restrict__ kf)
{
  const int lane = threadIdx.x & 63;
  const int wv   = threadIdx.x >> 6;
  const int b    = blockIdx.x;
  if (b < NND/4) {
    const int v = b*4 + wv;
    float a1 = b_gate[lane];
    float a2 = 0.f;
    const float* nrow = nf + v*CS;
    #pragma unroll
    for (int c = 0; c < CS; ++c) {
      const float x = nrow[c];                 // wave-uniform address -> broadcast
      a1 = fmaf(x, w_gate[c*CZ + lane], a1);   // coalesced across lanes
      a2 = fmaf(x, w_gate[(CS+c)*CZ + lane], a2);
    }
    g1[v*CZ + lane] = a1;
    g2[v*CZ + lane] = a2;
  } else {
    const int e = (b - NND/4)*4 + wv;
    const float* erow = ef + e*CZ;
    float a = b_edge[lane];
    #pragma unroll
    for (int c = 0; c < CZ; ++c)
      a = fmaf(erow[c], w_edge[c*CZ + lane], a);
    kf[e*CZ + lane] = a;
  }
}

// ---------------------------------------------------------------------------
// Kernel M: one block (256 threads) per node n. Thread p handles pair
// (i = p&15, j = p>>4). Computes rbf[64] in regs, 64x64 matvec vs w_db via
// uniform (scalar) loads, gate, kf product, shfl reduce over i, LayerNorm,
// writes x-hat to out (projected in-place by kernel C afterwards).
// ---------------------------------------------------------------------------
__global__ __launch_bounds__(256) void triangle_main_kernel(
    const float* __restrict__ trans, const int* __restrict__ eidx,
    const float* __restrict__ g1, const float* __restrict__ g2,
    const float* __restrict__ kf,
    const float* __restrict__ w_db, const float* __restrict__ b_db,
    const float* __restrict__ ln_g, const float* __restrict__ ln_b,
    float* __restrict__ out)
{
  __shared__ float t_l[KNB][4];
  __shared__ int   idx_l[KNB];
  __shared__ float G1l[KNB][CZ+4];   // pad to 68 floats: kills bank conflicts
  __shared__ float G2l[KNB][CZ+4];
  __shared__ float kfl[KNB][CZ+4];
  __shared__ float upd_l[KNB][CZ+4];

  const int n = blockIdx.x;
  const int p = threadIdx.x;
  const int i = p & 15;
  const int j = p >> 4;

  if (p < KNB) {
    const int s = eidx[n*KNB + p];   // edge_index row 0 (src), int32
    idx_l[p] = s;
    t_l[p][0] = trans[s*3+0];
    t_l[p][1] = trans[s*3+1];
    t_l[p][2] = trans[s*3+2];
  }
  __syncthreads();

  {
    const int r  = p >> 4;
    const int c0 = (p & 15) * 4;
    const int s  = idx_l[r];
    #pragma unroll
    for (int c = 0; c < 4; ++c) {
      G1l[r][c0+c] = g1[s*CZ + c0 + c];
      G2l[r][c0+c] = g2[s*CZ + c0 + c];
      kfl[r][c0+c] = kf[(n*KNB + r)*CZ + c0 + c];
    }
  }
  __syncthreads();

  // pairwise distance (EPS added per component, as in reference)
  const float dx = t_l[i][0] - t_l[j][0] + 1e-8f;
  const float dy = t_l[i][1] - t_l[j][1] + 1e-8f;
  const float dz = t_l[i][2] - t_l[j][2] + 1e-8f;
  const float d  = sqrtf(fmaf(dx,dx, fmaf(dy,dy, dz*dz)));

  // rbf[r] = exp(-((d - mu_r)/sigma)^2), mu_r = 20r/63, sigma = 20/64
  float rbf[NRBF];
  #pragma unroll
  for (int r = 0; r < NRBF; ++r) {
    const float u = (d - (20.0f/63.0f)*(float)r) * 3.2f;
    rbf[r] = __expf(-u*u);
  }

  // main loop: 4 chunks of 16 output channels
  for (int hc = 0; hc < 4; ++hc) {
    float acc[16];
    #pragma unroll
    for (int h = 0; h < 16; ++h) acc[h] = b_db[hc*16 + h];   // uniform scalar load
    #pragma unroll
    for (int r = 0; r < NRBF; ++r) {
      const float rv = rbf[r];
      const float* wrow = w_db + r*CZ + hc*16;               // uniform -> s_load
      #pragma unroll
      for (int h = 0; h < 16; ++h)
        acc[h] = fmaf(rv, wrow[h], acc[h]);
    }
    float keep = 0.f;
    #pragma unroll
    for (int h = 0; h < 16; ++h) {
      const int hh = hc*16 + h;
      const float gx   = G1l[i][hh] + G2l[j][hh];            // b_gate folded in G1
      const float gate = 1.0f / (1.0f + __expf(-gx));
      float val = gate * acc[h] * kfl[i][hh];
      // reduce over i: lanes within each 16-lane group
      val += __shfl_xor(val, 1);
      val += __shfl_xor(val, 2);
      val += __shfl_xor(val, 4);
      val += __shfl_xor(val, 8);
      if (h == i) keep = val;   // compile-time h vs runtime i -> cndmask select
    }
    upd_l[j][hc*16 + i] = keep;
  }
  __syncthreads();

  // LayerNorm per row j (each 16-lane group owns one row)
  const float x0 = upd_l[j][i*4+0];
  const float x1 = upd_l[j][i*4+1];
  const float x2 = upd_l[j][i*4+2];
  const float x3 = upd_l[j][i*4+3];
  float s1 = x0+x1+x2+x3;
  float s2 = x0*x0 + x1*x1 + x2*x2 + x3*x3;
  s1 += __shfl_xor(s1,1); s1 += __shfl_xor(s1,2); s1 += __shfl_xor(s1,4); s1 += __shfl_xor(s1,8);
  s2 += __shfl_xor(s2,1); s2 += __shfl_xor(s2,2); s2 += __shfl_xor(s2,4); s2 += __shfl_xor(s2,8);
  const float mean = s1 * (1.0f/64.0f);
  const float var  = s2 * (1.0f/64.0f) - mean*mean;
  const float rstd = rsqrtf(var + 1e-5f);
  const float xs[4] = {x0,x1,x2,x3};
  const int e = n*KNB + j;
  #pragma unroll
  for (int c = 0; c < 4; ++c) {
    const int hh = i*4 + c;
    out[e*CZ + hh] = (xs[c] - mean) * rstd * ln_g[hh] + ln_b[hh];
  }
}

// ---------------------------------------------------------------------------
// Kernel C: in-place projection out = xhat @ w_out + b_out.
// One wave per row; w_out column held in 64 VGPRs; row broadcast via readlane.
// ---------------------------------------------------------------------------
__global__ __launch_bounds__(256) void proj_kernel(
    const float* __restrict__ w_out, const float* __restrict__ b_out,
    float* __restrict__ out)
{
  const int lane = threadIdx.x & 63;
  const int wid  = (int)((blockIdx.x * blockDim.x + threadIdx.x) >> 6);
  const int nw   = (int)((gridDim.x * blockDim.x) >> 6);
  float w[CZ];
  #pragma unroll
  for (int c = 0; c < CZ; ++c) w[c] = w_out[c*CZ + lane];
  const float bo = b_out[lane];
  for (int e = wid; e < NE; e += nw) {
    const float x = out[e*CZ + lane];
    float acc = bo;
    #pragma unroll
    for (int c = 0; c < CZ; ++c) {
      const float xc = __int_as_float(__builtin_amdgcn_readlane(__float_as_int(x), c));
      acc = fmaf(xc, w[c], acc);
    }
    out[e*CZ + lane] = acc;   // x already in registers; in-place safe per-wave
  }
}

extern "C" void kernel_launch(void* const* d_in, const int* in_sizes, int n_in,
                              void* d_out, int out_size, void* d_ws, size_t ws_size,
                              hipStream_t stream)
{
  const float* nf     = (const float*)d_in[0];
  const float* trans  = (const float*)d_in[1];
  const float* ef     = (const float*)d_in[2];
  const int*   eidx   = (const int*)d_in[3];   // edge_index (2,E) int32; row 0 = src
  const float* w_gate = (const float*)d_in[4];
  const float* b_gate = (const float*)d_in[5];
  const float* w_db   = (const float*)d_in[6];
  const float* b_db   = (const float*)d_in[7];
  const float* w_edge = (const float*)d_in[8];
  const float* b_edge = (const float*)d_in[9];
  const float* ln_g   = (const float*)d_in[10];
  const float* ln_b   = (const float*)d_in[11];
  const float* w_out  = (const float*)d_in[12];
  const float* b_out  = (const float*)d_in[13];
  float* out = (float*)d_out;

  float* g1 = (float*)d_ws;            // [2000][64]
  float* g2 = g1 + NND*CZ;             // [2000][64]
  float* kf = g2 + NND*CZ;             // [32000][64]  (total ws use: ~9.2 MB)

  precompute_kernel<<<NND/4 + NE/4, 256, 0, stream>>>(
      nf, ef, w_gate, b_gate, w_edge, b_edge, g1, g2, kf);
  triangle_main_kernel<<<NND, 256, 0, stream>>>(
      trans, eidx, g1, g2, kf, w_db, b_db, ln_g, ln_b, out);
  proj_kernel<<<512, 256, 0, stream>>>(w_out, b_out, out);
}

// Round 2
// 71.759 us; speedup vs baseline: 1.9952x; 1.9952x over previous
//
#include <hip/hip_runtime.h>

#define NND 2000
#define KNB 16
#define CS 128
#define CZ 64
#define NRBF 64
#define NE (NND*KNB)

typedef __attribute__((ext_vector_type(8))) short short8;
typedef __attribute__((ext_vector_type(4))) float f32x4;
typedef __attribute__((ext_vector_type(4))) unsigned int uint4v;

__device__ __forceinline__ unsigned short f2bf(float f) {
  unsigned int u = __float_as_uint(f);
  u += 0x7fffu + ((u >> 16) & 1u);      // RNE round to bf16 (normals)
  return (unsigned short)(u >> 16);
}

// ---------------------------------------------------------------------------
// Kernel P: per-node gate projections G1/G2 (b_gate folded into G1),
// per-edge kf = ef @ w_edge + b_edge, and bias2 = b_out + ln_b @ w_out.
// ---------------------------------------------------------------------------
__global__ __launch_bounds__(256) void precompute_kernel(
    const float* __restrict__ nf, const float* __restrict__ ef,
    const float* __restrict__ w_gate, const float* __restrict__ b_gate,
    const float* __restrict__ w_edge, const float* __restrict__ b_edge,
    const float* __restrict__ ln_b, const float* __restrict__ w_out,
    const float* __restrict__ b_out,
    float* __restrict__ g1, float* __restrict__ g2, float* __restrict__ kf,
    float* __restrict__ bias2)
{
  const int lane = threadIdx.x & 63;
  const int wv   = threadIdx.x >> 6;
  const int b    = blockIdx.x;
  if (b < NND/4) {
    const int v = b*4 + wv;
    float a1 = b_gate[lane];
    float a2 = 0.f;
    const float* nrow = nf + v*CS;
    #pragma unroll
    for (int c = 0; c < CS; ++c) {
      const float x = nrow[c];
      a1 = fmaf(x, w_gate[c*CZ + lane], a1);
      a2 = fmaf(x, w_gate[(CS+c)*CZ + lane], a2);
    }
    g1[v*CZ + lane] = a1;
    g2[v*CZ + lane] = a2;
  } else if (b < NND/4 + NE/4) {
    const int e = (b - NND/4)*4 + wv;
    const float* erow = ef + e*CZ;
    float a = b_edge[lane];
    #pragma unroll
    for (int c = 0; c < CZ; ++c)
      a = fmaf(erow[c], w_edge[c*CZ + lane], a);
    kf[e*CZ + lane] = a;
  } else {
    if (wv == 0) {
      float a = b_out[lane];
      #pragma unroll
      for (int c = 0; c < CZ; ++c)
        a = fmaf(ln_b[c], w_out[c*CZ + lane], a);
      bias2[lane] = a;
    }
  }
}

// ---------------------------------------------------------------------------
// Fused main kernel: one block (4 waves) per node.
//   MFMA1: DB = rbf(dist) @ w_db   (A: per-pair rbf bf16 in LDS, 2 K-halves)
//   VALU : gate sigmoid * (DB+b_db) * kf, reduce over i, in-register LN
//   MFMA2: out = xhat @ (ln_g*w_out) + bias2
// C-frag mapping (16x16x32): row = 4*q+reg (local pair), col = c (h).
// ---------------------------------------------------------------------------
__global__ __launch_bounds__(256, 3) void fused_main_kernel(
    const float* __restrict__ trans, const int* __restrict__ eidx,
    const float* __restrict__ g1, const float* __restrict__ g2,
    const float* __restrict__ kf,
    const float* __restrict__ w_db, const float* __restrict__ b_db,
    const float* __restrict__ ln_g, const float* __restrict__ w_out,
    const float* __restrict__ bias2,
    float* __restrict__ out)
{
  __shared__ unsigned short rbfl[256][40];   // per-pair 32 bf16 (one K-half) + pad
  __shared__ unsigned short wdbT[64][72];    // w_db^T bf16: [h][r] + pad
  __shared__ float G1l[KNB][68];
  __shared__ float G2l[KNB][68];
  __shared__ float kfl[KNB][68];
  __shared__ unsigned short xh[KNB][72];     // xhat bf16 [j][h] + pad
  __shared__ float t_l[KNB][4];
  __shared__ int   idx_l[KNB];

  const int n = blockIdx.x;
  const int p = threadIdx.x;
  const int w = p >> 6;        // wave
  const int l = p & 63;
  const int q = l >> 4;        // quarter-group
  const int c = l & 15;

  if (p < KNB) {
    const int s = eidx[n*KNB + p];
    idx_l[p] = s;
    t_l[p][0] = trans[s*3+0];
    t_l[p][1] = trans[s*3+1];
    t_l[p][2] = trans[s*3+2];
  }
  // stage w_db^T as bf16 (once per block; reads coalesced)
  #pragma unroll
  for (int t = 0; t < 16; ++t) {
    const int idx = p + 256*t;
    wdbT[idx & 63][idx >> 6] = f2bf(w_db[idx]);
  }
  __syncthreads();

  { // gather G1/G2/kf rows into LDS (float4)
    const int r = p >> 4, c0 = (p & 15) * 4;
    const int s = idx_l[r];
    *(f32x4*)&G1l[r][c0] = *(const f32x4*)&g1[s*CZ + c0];
    *(f32x4*)&G2l[r][c0] = *(const f32x4*)&g2[s*CZ + c0];
    *(f32x4*)&kfl[r][c0] = *(const f32x4*)&kf[(n*KNB + r)*CZ + c0];
  }

  // this thread's pair: i = p&15, j = p>>4 (pair index == p)
  const int pi = p & 15, pj = p >> 4;
  const float dx = t_l[pi][0] - t_l[pj][0] + 1e-8f;
  const float dy = t_l[pi][1] - t_l[pj][1] + 1e-8f;
  const float dz = t_l[pi][2] - t_l[pj][2] + 1e-8f;
  const float d32 = sqrtf(fmaf(dx,dx, fmaf(dy,dy, dz*dz))) * 3.2f;  // d/sigma

  // ---- MFMA1: DB = rbf @ w_db, two K=32 halves -------------------------
  f32x4 acc[4][4] = {};   // [mtile][ntile]
  #pragma unroll
  for (int s = 0; s < 2; ++s) {
    unsigned int pk[16];
    #pragma unroll
    for (int t = 0; t < 16; ++t) {
      // r = 32*s + 2*t; (d - mu_r)/sigma = d*3.2 - r*(64/63)
      const float u0 = d32 - (float)(32*s + 2*t) * 1.0158730158730158f;
      const float u1 = u0 - 1.0158730158730158f;
      pk[t] = (unsigned int)f2bf(__expf(-u0*u0))
            | ((unsigned int)f2bf(__expf(-u1*u1)) << 16);
    }
    #pragma unroll
    for (int t = 0; t < 4; ++t)
      *(uint4v*)&rbfl[p][8*t] = *(const uint4v*)&pk[4*t];
    __syncthreads();

    short8 bfr[4];
    #pragma unroll
    for (int nt = 0; nt < 4; ++nt)
      bfr[nt] = *(const short8*)&wdbT[16*nt + c][q*8 + 32*s];
    #pragma unroll
    for (int m = 0; m < 4; ++m) {
      const short8 af = *(const short8*)&rbfl[64*w + 16*m + c][q*8];
      #pragma unroll
      for (int nt = 0; nt < 4; ++nt)
        acc[m][nt] = __builtin_amdgcn_mfma_f32_16x16x32_bf16(af, bfr[nt], acc[m][nt], 0, 0, 0);
    }
    __syncthreads();
  }

  // proj B-fragments: w_out with ln_g folded in (issued early to hide latency)
  short8 wb[2];
  #pragma unroll
  for (int s = 0; s < 2; ++s) {
    short8 v;
    #pragma unroll
    for (int t = 0; t < 8; ++t) {
      const int k = q*8 + 32*s + t;
      v[t] = (short)f2bf(w_out[k*CZ + 16*w + c] * ln_g[k]);
    }
    wb[s] = v;
  }

  float bdb[4];
  #pragma unroll
  for (int nt = 0; nt < 4; ++nt) bdb[nt] = b_db[16*nt + c];

  // ---- gate * (DB + b_db) * kf, reduce over i --------------------------
  // C frag: local pair = 16*m + 4*q + reg  ->  i = 4*q+reg, j = 4*w+m, h = 16*nt+c
  float g1v[4][4], kfv[4][4];
  #pragma unroll
  for (int nt = 0; nt < 4; ++nt)
    #pragma unroll
    for (int r = 0; r < 4; ++r) {
      g1v[nt][r] = G1l[4*q + r][16*nt + c];
      kfv[nt][r] = kfl[4*q + r][16*nt + c];
    }

  float upd[4][4];
  #pragma unroll
  for (int m = 0; m < 4; ++m) {
    #pragma unroll
    for (int nt = 0; nt < 4; ++nt) {
      const float g2v = G2l[4*w + m][16*nt + c];
      float ss = 0.f;
      #pragma unroll
      for (int r = 0; r < 4; ++r) {
        const float gate = __builtin_amdgcn_rcpf(1.0f + __expf(-(g1v[nt][r] + g2v)));
        ss = fmaf(gate * (acc[m][nt][r] + bdb[nt]), kfv[nt][r], ss);
      }
      ss += __shfl_xor(ss, 16);
      ss += __shfl_xor(ss, 32);
      upd[m][nt] = ss;
    }
  }

  // ---- in-register LayerNorm (rows j = 4w+m are wave-local) ------------
  #pragma unroll
  for (int m = 0; m < 4; ++m) {
    float s1 = (upd[m][0] + upd[m][1]) + (upd[m][2] + upd[m][3]);
    float s2 = fmaf(upd[m][0], upd[m][0],
               fmaf(upd[m][1], upd[m][1],
               fmaf(upd[m][2], upd[m][2], upd[m][3]*upd[m][3])));
    #pragma unroll
    for (int mk = 1; mk <= 8; mk <<= 1) {
      s1 += __shfl_xor(s1, mk);
      s2 += __shfl_xor(s2, mk);
    }
    const float mean = s1 * 0.015625f;
    const float var  = fmaf(s2, 0.015625f, -mean*mean);
    const float rstd = rsqrtf(var + 1e-5f);
    #pragma unroll
    for (int nt = 0; nt < 4; ++nt)
      if (nt == q)   // each quarter-group writes its ntile's 16 channels
        xh[4*w + m][16*q + c] = f2bf((upd[m][nt] - mean) * rstd);
  }
  __syncthreads();

  // ---- MFMA2: out = xhat @ (ln_g*w_out) + bias2 ------------------------
  f32x4 acc2 = {};
  #pragma unroll
  for (int s = 0; s < 2; ++s) {
    const short8 af = *(const short8*)&xh[c][q*8 + 32*s];
    acc2 = __builtin_amdgcn_mfma_f32_16x16x32_bf16(af, wb[s], acc2, 0, 0, 0);
  }
  const float bo = bias2[16*w + c];
  #pragma unroll
  for (int r = 0; r < 4; ++r)
    out[(n*KNB + 4*q + r)*CZ + 16*w + c] = acc2[r] + bo;
}

extern "C" void kernel_launch(void* const* d_in, const int* in_sizes, int n_in,
                              void* d_out, int out_size, void* d_ws, size_t ws_size,
                              hipStream_t stream)
{
  const float* nf     = (const float*)d_in[0];
  const float* trans  = (const float*)d_in[1];
  const float* ef     = (const float*)d_in[2];
  const int*   eidx   = (const int*)d_in[3];
  const float* w_gate = (const float*)d_in[4];
  const float* b_gate = (const float*)d_in[5];
  const float* w_db   = (const float*)d_in[6];
  const float* b_db   = (const float*)d_in[7];
  const float* w_edge = (const float*)d_in[8];
  const float* b_edge = (const float*)d_in[9];
  const float* ln_g   = (const float*)d_in[10];
  const float* ln_b   = (const float*)d_in[11];
  const float* w_out  = (const float*)d_in[12];
  const float* b_out  = (const float*)d_in[13];
  float* out = (float*)d_out;

  float* g1    = (float*)d_ws;           // [2000][64]
  float* g2    = g1 + NND*CZ;            // [2000][64]
  float* kf    = g2 + NND*CZ;            // [32000][64]
  float* bias2 = kf + NE*CZ;             // [64]

  precompute_kernel<<<NND/4 + NE/4 + 1, 256, 0, stream>>>(
      nf, ef, w_gate, b_gate, w_edge, b_edge, ln_b, w_out, b_out,
      g1, g2, kf, bias2);
  fused_main_kernel<<<NND, 256, 0, stream>>>(
      trans, eidx, g1, g2, kf, w_db, b_db, ln_g, w_out, bias2, out);
}

// Round 3
// 41.522 us; speedup vs baseline: 3.4482x; 1.7282x over previous
//
#include <hip/hip_runtime.h>

#define NND 2000
#define KNB 16
#define CS 128
#define CZ 64
#define NE (NND*KNB)

typedef __attribute__((ext_vector_type(8))) short short8;
typedef __attribute__((ext_vector_type(4))) float f32x4;
typedef __attribute__((ext_vector_type(4))) unsigned int uint4v;

__device__ __forceinline__ unsigned short f2bf(float f) {
  unsigned int u = __float_as_uint(f);
  u += 0x7fffu + ((u >> 16) & 1u);      // RNE round to bf16 (normals)
  return (unsigned short)(u >> 16);
}

__device__ __forceinline__ float fexp2(float x) {
#if __has_builtin(__builtin_amdgcn_exp2f)
  return __builtin_amdgcn_exp2f(x);     // v_exp_f32 (2^x) directly
#else
  return __expf(0.6931471805599453f * x);
#endif
}

// ---------------------------------------------------------------------------
// Precompute: per-node gate logits G1/G2 (b_gate folded into G1, log2e
// pre-multiplied so the gate uses exp2 directly) and bias2 = b_out+ln_b@w_out.
// ---------------------------------------------------------------------------
__global__ __launch_bounds__(256) void precompute_kernel(
    const float* __restrict__ nf,
    const float* __restrict__ w_gate, const float* __restrict__ b_gate,
    const float* __restrict__ ln_b, const float* __restrict__ w_out,
    const float* __restrict__ b_out,
    float* __restrict__ g1, float* __restrict__ g2, float* __restrict__ bias2)
{
  const int lane = threadIdx.x & 63;
  const int wv   = threadIdx.x >> 6;
  const int b    = blockIdx.x;
  if (b < NND/4) {
    const int v = b*4 + wv;
    float a1 = b_gate[lane];
    float a2 = 0.f;
    const float* nrow = nf + v*CS;
    #pragma unroll
    for (int cc = 0; cc < CS; ++cc) {
      const float x = nrow[cc];
      a1 = fmaf(x, w_gate[cc*CZ + lane], a1);
      a2 = fmaf(x, w_gate[(CS+cc)*CZ + lane], a2);
    }
    g1[v*CZ + lane] = a1 * 1.4426950408889634f;   // log2e folded
    g2[v*CZ + lane] = a2 * 1.4426950408889634f;
  } else if (wv == 0) {
    float a = b_out[lane];
    #pragma unroll
    for (int cc = 0; cc < CZ; ++cc)
      a = fmaf(ln_b[cc], w_out[cc*CZ + lane], a);
    bias2[lane] = a;
  }
}

// ---------------------------------------------------------------------------
// Fused main kernel: one block (4 waves) per node.
//   MFMA0: kf   = ef_tile @ w_edge + b_edge          (block-local edges!)
//   MFMA1: DB   = rbf(dist) @ w_db                   (2 K=32 halves)
//   VALU : sigmoid-gate * (DB+b_db) * kf, reduce over i, in-register LN
//   MFMA2: out  = xhat @ (ln_g*w_out) + bias2
// Frag maps (verified r2): A row=l&15,k=(l>>4)*8+t; B col=l&15,k=(l>>4)*8+t;
//                          C col=l&15, row=4*(l>>4)+reg.
// ---------------------------------------------------------------------------
__global__ __launch_bounds__(256, 3) void fused_main_kernel(
    const float* __restrict__ trans, const int* __restrict__ eidx,
    const float* __restrict__ g1, const float* __restrict__ g2,
    const float* __restrict__ ef, const float* __restrict__ w_edge,
    const float* __restrict__ b_edge,
    const float* __restrict__ w_db, const float* __restrict__ b_db,
    const float* __restrict__ ln_g, const float* __restrict__ w_out,
    const float* __restrict__ bias2,
    float* __restrict__ out)
{
  __shared__ unsigned short wbuf[CZ][72];    // phase0: w_edgeT; later: w_dbT ([col][k])
  __shared__ unsigned short efl[KNB][72];    // ef tile bf16 [edge][k]
  __shared__ unsigned short rbfl[256][40];   // per-pair 32 bf16 (one K-half)
  __shared__ float G1l[KNB][68];
  __shared__ float G2l[KNB][68];
  __shared__ float kfl[KNB][68];
  __shared__ unsigned short xh[KNB][72];     // xhat bf16 [j][h]
  __shared__ float t_l[KNB][4];
  __shared__ int   idx_l[KNB];

  const int n = blockIdx.x;
  const int p = threadIdx.x;
  const int w = p >> 6;
  const int l = p & 63;
  const int q = l >> 4;
  const int c = l & 15;

  if (p < KNB) {
    const int s = eidx[n*KNB + p];
    idx_l[p] = s;
    t_l[p][0] = trans[s*3+0];
    t_l[p][1] = trans[s*3+1];
    t_l[p][2] = trans[s*3+2];
  }
  { // stage ef tile as bf16 (float4 loads, coalesced)
    const int r = p >> 4, c0 = (p & 15) * 4;
    const f32x4 v = *(const f32x4*)&ef[(n*KNB + r)*CZ + c0];
    #pragma unroll
    for (int t = 0; t < 4; ++t) efl[r][c0+t] = f2bf(v[t]);
  }
  // stage w_edge^T as bf16: wbuf[col][k]
  #pragma unroll
  for (int t = 0; t < 16; ++t) {
    const int e = p + 256*t;
    wbuf[e & 63][e >> 6] = f2bf(w_edge[e]);
  }
  __syncthreads();   // b1: idx/t/efl/w_edgeT visible

  { // gather G rows (needs idx_l)
    const int r = p >> 4, c0 = (p & 15) * 4;
    const int s = idx_l[r];
    *(f32x4*)&G1l[r][c0] = *(const f32x4*)&g1[s*CZ + c0];
    *(f32x4*)&G2l[r][c0] = *(const f32x4*)&g2[s*CZ + c0];
  }
  { // MFMA0: kf tile; wave w owns cols 16w..16w+15
    f32x4 ak = {};
    #pragma unroll
    for (int s = 0; s < 2; ++s) {
      const short8 af = *(const short8*)&efl[c][q*8 + 32*s];
      const short8 bf = *(const short8*)&wbuf[16*w + c][q*8 + 32*s];
      ak = __builtin_amdgcn_mfma_f32_16x16x32_bf16(af, bf, ak, 0, 0, 0);
    }
    const float be = b_edge[16*w + c];
    #pragma unroll
    for (int r = 0; r < 4; ++r)
      kfl[4*q + r][16*w + c] = ak[r] + be;
  }

  // distance, pre-scaled so rbf = exp2(-(u')^2)
  const int pi = p & 15, pj = p >> 4;
  const float dx = t_l[pi][0] - t_l[pj][0] + 1e-8f;
  const float dy = t_l[pi][1] - t_l[pj][1] + 1e-8f;
  const float dz = t_l[pi][2] - t_l[pj][2] + 1e-8f;
  const float dsc = sqrtf(fmaf(dx,dx, fmaf(dy,dy, dz*dz))) * 3.8435917081166394f; // 3.2*sqrt(log2e)
  const float STEP = 1.2201878439258035f;  // (20/63)*3.2*sqrt(log2e)

  __syncthreads();   // b2: w_edgeT consumed, kfl written

  // stage w_db^T into the same buffer: wbuf[h][r]
  #pragma unroll
  for (int t = 0; t < 16; ++t) {
    const int e = p + 256*t;
    wbuf[e & 63][e >> 6] = f2bf(w_db[e]);
  }

  // ---- MFMA1: DB = rbf @ w_db, two K=32 halves -------------------------
  f32x4 acc[4][4] = {};   // [mtile][ntile]
  #pragma unroll
  for (int s2 = 0; s2 < 2; ++s2) {
    unsigned int pk[16];
    #pragma unroll
    for (int t = 0; t < 16; ++t) {
      const float u0 = dsc - (float)(32*s2 + 2*t) * STEP;
      const float u1 = u0 - STEP;
      pk[t] = (unsigned int)f2bf(fexp2(-u0*u0))
            | ((unsigned int)f2bf(fexp2(-u1*u1)) << 16);
    }
    #pragma unroll
    for (int t = 0; t < 4; ++t)
      *(uint4v*)&rbfl[p][8*t] = *(const uint4v*)&pk[4*t];
    __syncthreads();   // b3/b5 (b3 also covers w_dbT staging)

    short8 bfr[4];
    #pragma unroll
    for (int nt = 0; nt < 4; ++nt)
      bfr[nt] = *(const short8*)&wbuf[16*nt + c][q*8 + 32*s2];
    #pragma unroll
    for (int m = 0; m < 4; ++m) {
      const short8 af = *(const short8*)&rbfl[64*w + 16*m + c][q*8];
      #pragma unroll
      for (int nt = 0; nt < 4; ++nt)
        acc[m][nt] = __builtin_amdgcn_mfma_f32_16x16x32_bf16(af, bfr[nt], acc[m][nt], 0, 0, 0);
    }
    __syncthreads();   // b4/b6
  }

  // proj B-fragments: w_out with ln_g folded in
  short8 wb[2];
  #pragma unroll
  for (int s = 0; s < 2; ++s) {
    short8 v;
    #pragma unroll
    for (int t = 0; t < 8; ++t) {
      const int k = q*8 + 32*s + t;
      v[t] = (short)f2bf(w_out[k*CZ + 16*w + c] * ln_g[k]);
    }
    wb[s] = v;
  }

  float bdb[4];
  #pragma unroll
  for (int nt = 0; nt < 4; ++nt) bdb[nt] = b_db[16*nt + c];

  // ---- gate * (DB + b_db) * kf, reduce over i --------------------------
  // C frag: local pair = 16*m + 4*q + r  ->  i = 4*q+r, j = 4*w+m, h = 16*nt+c
  float g1v[4][4], kfv[4][4];
  #pragma unroll
  for (int nt = 0; nt < 4; ++nt)
    #pragma unroll
    for (int r = 0; r < 4; ++r) {
      g1v[nt][r] = G1l[4*q + r][16*nt + c];
      kfv[nt][r] = kfl[4*q + r][16*nt + c];
    }

  float upd[4][4];
  #pragma unroll
  for (int m = 0; m < 4; ++m) {
    #pragma unroll
    for (int nt = 0; nt < 4; ++nt) {
      const float g2vm = G2l[4*w + m][16*nt + c];
      float ss = 0.f;
      #pragma unroll
      for (int r = 0; r < 4; ++r) {
        const float gate = __builtin_amdgcn_rcpf(1.0f + fexp2(-(g1v[nt][r] + g2vm)));
        ss = fmaf(gate * (acc[m][nt][r] + bdb[nt]), kfv[nt][r], ss);
      }
      ss += __shfl_xor(ss, 16);
      ss += __shfl_xor(ss, 32);
      upd[m][nt] = ss;
    }
  }

  // ---- in-register LayerNorm (rows j = 4w+m are wave-local) ------------
  #pragma unroll
  for (int m = 0; m < 4; ++m) {
    float s1 = (upd[m][0] + upd[m][1]) + (upd[m][2] + upd[m][3]);
    float s2 = fmaf(upd[m][0], upd[m][0],
               fmaf(upd[m][1], upd[m][1],
               fmaf(upd[m][2], upd[m][2], upd[m][3]*upd[m][3])));
    #pragma unroll
    for (int mk = 1; mk <= 8; mk <<= 1) {
      s1 += __shfl_xor(s1, mk);
      s2 += __shfl_xor(s2, mk);
    }
    const float mean = s1 * 0.015625f;
    const float var  = fmaf(s2, 0.015625f, -mean*mean);
    const float rstd = rsqrtf(var + 1e-5f);
    #pragma unroll
    for (int nt = 0; nt < 4; ++nt)
      if (nt == q)
        xh[4*w + m][16*q + c] = f2bf((upd[m][nt] - mean) * rstd);
  }
  __syncthreads();   // b7: xh visible

  // ---- MFMA2: out = xhat @ (ln_g*w_out) + bias2 ------------------------
  f32x4 acc2 = {};
  #pragma unroll
  for (int s = 0; s < 2; ++s) {
    const short8 af = *(const short8*)&xh[c][q*8 + 32*s];
    acc2 = __builtin_amdgcn_mfma_f32_16x16x32_bf16(af, wb[s], acc2, 0, 0, 0);
  }
  const float bo = bias2[16*w + c];
  #pragma unroll
  for (int r = 0; r < 4; ++r)
    out[(n*KNB + 4*q + r)*CZ + 16*w + c] = acc2[r] + bo;
}

extern "C" void kernel_launch(void* const* d_in, const int* in_sizes, int n_in,
                              void* d_out, int out_size, void* d_ws, size_t ws_size,
                              hipStream_t stream)
{
  const float* nf     = (const float*)d_in[0];
  const float* trans  = (const float*)d_in[1];
  const float* ef     = (const float*)d_in[2];
  const int*   eidx   = (const int*)d_in[3];
  const float* w_gate = (const float*)d_in[4];
  const float* b_gate = (const float*)d_in[5];
  const float* w_db   = (const float*)d_in[6];
  const float* b_db   = (const float*)d_in[7];
  const float* w_edge = (const float*)d_in[8];
  const float* b_edge = (const float*)d_in[9];
  const float* ln_g   = (const float*)d_in[10];
  const float* ln_b   = (const float*)d_in[11];
  const float* w_out  = (const float*)d_in[12];
  const float* b_out  = (const float*)d_in[13];
  float* out = (float*)d_out;

  float* g1    = (float*)d_ws;           // [2000][64]
  float* g2    = g1 + NND*CZ;            // [2000][64]
  float* bias2 = g2 + NND*CZ;            // [64]

  precompute_kernel<<<NND/4 + 1, 256, 0, stream>>>(
      nf, w_gate, b_gate, ln_b, w_out, b_out, g1, g2, bias2);
  fused_main_kernel<<<NND, 256, 0, stream>>>(
      trans, eidx, g1, g2, ef, w_edge, b_edge, w_db, b_db,
      ln_g, w_out, bias2, out);
}

// Round 4
// 36.178 us; speedup vs baseline: 3.9575x; 1.1477x over previous
//
#include <hip/hip_runtime.h>

#define NND 2000
#define KNB 16
#define CS 128
#define CZ 64
#define NE (NND*KNB)

typedef __attribute__((ext_vector_type(8))) short short8;
typedef __attribute__((ext_vector_type(4))) float f32x4;
typedef __attribute__((ext_vector_type(2))) unsigned int uint2v;

__device__ __forceinline__ unsigned short f2bf(float f) {
  unsigned int u = __float_as_uint(f);
  u += 0x7fffu + ((u >> 16) & 1u);      // RNE round to bf16
  return (unsigned short)(u >> 16);
}

__device__ __forceinline__ float fexp2(float x) {
#if __has_builtin(__builtin_amdgcn_exp2f)
  return __builtin_amdgcn_exp2f(x);
#else
  return __expf(0.6931471805599453f * x);
#endif
}

// ---------------------------------------------------------------------------
// Precompute:
//   blocks [0,500): per-node gate logits G1/G2 (b_gate in G1, log2e folded)
//   block 500: wave0 bias2 = b_out + ln_b@w_out
//              wave1 wdbF  = w_db  B-fragments (bf16, MFMA layout)
//              wave2 wedF  = w_edge B-fragments
//              wave3 woF   = (ln_g*w_out) B-fragments
// Fragment layouts (16x16x32 bf16 B-frag: col = l&15, k = (l>>4)*8 + t):
//   wdbF[((s*4+nt)*64 + l)*8 + t] = bf16(w_db[(32s+8q+t)*64 + 16nt+c])
//   wedF[((s*256 + p))*8 + t]     = bf16(w_edge[(32s+8q+t)*64 + 16(p>>6)+c])
//   woF [((s*256 + p))*8 + t]     = bf16(w_out [(32s+8q+t)*64 + 16(p>>6)+c] * ln_g[k])
// ---------------------------------------------------------------------------
__global__ __launch_bounds__(256) void precompute_kernel(
    const float* __restrict__ nf,
    const float* __restrict__ w_gate, const float* __restrict__ b_gate,
    const float* __restrict__ ln_b, const float* __restrict__ w_out,
    const float* __restrict__ b_out,
    const float* __restrict__ w_db, const float* __restrict__ w_edge,
    const float* __restrict__ ln_g,
    float* __restrict__ g1, float* __restrict__ g2, float* __restrict__ bias2,
    unsigned short* __restrict__ wdbF, unsigned short* __restrict__ wedF,
    unsigned short* __restrict__ woF)
{
  const int lane = threadIdx.x & 63;
  const int wv   = threadIdx.x >> 6;
  const int b    = blockIdx.x;
  if (b < NND/4) {
    const int v = b*4 + wv;
    float a1 = b_gate[lane];
    float a2 = 0.f;
    const float* nrow = nf + v*CS;
    #pragma unroll
    for (int cc = 0; cc < CS; ++cc) {
      const float x = nrow[cc];
      a1 = fmaf(x, w_gate[cc*CZ + lane], a1);
      a2 = fmaf(x, w_gate[(CS+cc)*CZ + lane], a2);
    }
    g1[v*CZ + lane] = a1 * 1.4426950408889634f;   // log2e folded (exp2 gate)
    g2[v*CZ + lane] = a2 * 1.4426950408889634f;
  } else if (wv == 0) {
    float a = b_out[lane];
    #pragma unroll
    for (int cc = 0; cc < CZ; ++cc)
      a = fmaf(ln_b[cc], w_out[cc*CZ + lane], a);
    bias2[lane] = a;
  } else if (wv == 1) {
    for (int e = lane; e < 4096; e += 64) {
      const int entry = e >> 3, t = e & 7;
      const int l2 = entry & 63, sn = entry >> 6;
      const int s = sn >> 2, nt = sn & 3;
      const int q = l2 >> 4, c = l2 & 15;
      const int k = 32*s + 8*q + t, h = 16*nt + c;
      wdbF[e] = f2bf(w_db[k*CZ + h]);
    }
  } else if (wv == 2) {
    for (int e = lane; e < 4096; e += 64) {
      const int entry = e >> 3, t = e & 7;
      const int p2 = entry & 255, s = entry >> 8;
      const int q = (p2 >> 4) & 3, c = p2 & 15;
      const int col = 16*(p2 >> 6) + c, k = 32*s + 8*q + t;
      wedF[e] = f2bf(w_edge[k*CZ + col]);
    }
  } else {
    for (int e = lane; e < 4096; e += 64) {
      const int entry = e >> 3, t = e & 7;
      const int p2 = entry & 255, s = entry >> 8;
      const int q = (p2 >> 4) & 3, c = p2 & 15;
      const int col = 16*(p2 >> 6) + c, k = 32*s + 8*q + t;
      woF[e] = f2bf(w_out[k*CZ + col] * ln_g[k]);
    }
  }
}

// ---------------------------------------------------------------------------
// Fused main kernel: one block (4 waves) per node. 3 barriers total.
//   MFMA0: kf  = ef_tile @ w_edge + b_edge       (frags direct from global)
//   MFMA1: DB  = rbf(dist) @ w_db                (A-frags computed in regs)
//   VALU : sigmoid-gate * (DB+b_db) * kf, reduce over i, in-register LN
//   MFMA2: out = xhat @ (ln_g*w_out) + bias2
// ---------------------------------------------------------------------------
__global__ __launch_bounds__(256, 4) void fused_main_kernel(
    const float* __restrict__ trans, const int* __restrict__ eidx,
    const float* __restrict__ g1, const float* __restrict__ g2,
    const float* __restrict__ ef, const float* __restrict__ b_edge,
    const float* __restrict__ b_db, const float* __restrict__ bias2,
    const unsigned short* __restrict__ wdbF,
    const unsigned short* __restrict__ wedF,
    const unsigned short* __restrict__ woF,
    float* __restrict__ out)
{
  __shared__ unsigned short efl[KNB][72];    // ef tile bf16
  __shared__ float G1l[KNB][68];
  __shared__ float G2l[KNB][68];
  __shared__ float kfl[KNB][68];
  __shared__ unsigned short xh[KNB][72];     // xhat bf16
  __shared__ float t_l[KNB][4];
  __shared__ int   idx_l[KNB];

  const int n = blockIdx.x;
  const int p = threadIdx.x;
  const int w = p >> 6;
  const int l = p & 63;
  const int q = l >> 4;
  const int c = l & 15;

  if (p < KNB) {
    const int s = eidx[n*KNB + p];
    idx_l[p] = s;
    t_l[p][0] = trans[s*3+0];
    t_l[p][1] = trans[s*3+1];
    t_l[p][2] = trans[s*3+2];
  }
  { // stage ef tile as bf16 (coalesced float4 loads, packed b64 LDS writes)
    const int r = p >> 4, c0 = (p & 15) * 4;
    const f32x4 v = *(const f32x4*)&ef[(n*KNB + r)*CZ + c0];
    uint2v pk;
    pk[0] = (unsigned int)f2bf(v[0]) | ((unsigned int)f2bf(v[1]) << 16);
    pk[1] = (unsigned int)f2bf(v[2]) | ((unsigned int)f2bf(v[3]) << 16);
    *(uint2v*)&efl[r][c0] = pk;
  }

  // weight fragments straight from global (L2-resident, coalesced 16B)
  short8 wed[2], bfr[2][4];
  #pragma unroll
  for (int s = 0; s < 2; ++s) {
    wed[s] = *(const short8*)&wedF[(s*256 + p)*8];
    #pragma unroll
    for (int nt = 0; nt < 4; ++nt)
      bfr[s][nt] = *(const short8*)&wdbF[((s*4 + nt)*64 + l)*8];
  }
  const float be = b_edge[16*w + c];
  const float bo = bias2[16*w + c];
  float bdb[4];
  #pragma unroll
  for (int nt = 0; nt < 4; ++nt) bdb[nt] = b_db[16*nt + c];

  __syncthreads();   // b1: efl, t_l, idx_l visible

  { // gather G rows (needs idx_l)
    const int r = p >> 4, c0 = (p & 15) * 4;
    const int s = idx_l[r];
    *(f32x4*)&G1l[r][c0] = *(const f32x4*)&g1[s*CZ + c0];
    *(f32x4*)&G2l[r][c0] = *(const f32x4*)&g2[s*CZ + c0];
  }
  { // MFMA0: kf tile; wave w owns cols 16w..16w+15
    f32x4 ak = {};
    #pragma unroll
    for (int s = 0; s < 2; ++s) {
      const short8 af = *(const short8*)&efl[c][q*8 + 32*s];
      ak = __builtin_amdgcn_mfma_f32_16x16x32_bf16(af, wed[s], ak, 0, 0, 0);
    }
    #pragma unroll
    for (int r = 0; r < 4; ++r)
      kfl[4*q + r][16*w + c] = ak[r] + be;
  }

  // distances for the 4 A-frag rows this lane feeds: pair (i=c, j=4w+m)
  const float STEP = 1.2201878439258035f;   // (64/63)*sqrt(log2e)... pre-scaled
  float dsc[4];
  #pragma unroll
  for (int m = 0; m < 4; ++m) {
    const int j = 4*w + m;
    const float dx = t_l[c][0] - t_l[j][0] + 1e-8f;
    const float dy = t_l[c][1] - t_l[j][1] + 1e-8f;
    const float dz = t_l[c][2] - t_l[j][2] + 1e-8f;
    dsc[m] = sqrtf(fmaf(dx,dx, fmaf(dy,dy, dz*dz))) * 3.8435917081166394f;
  }
  const float qoff = (float)(8*q) * STEP;

  // ---- MFMA1: DB = rbf @ w_db, A-frags computed in registers -----------
  f32x4 acc[4][4] = {};   // [mtile][ntile]
  #pragma unroll
  for (int s = 0; s < 2; ++s) {
    const float soff = qoff + (float)(32*s) * STEP;
    #pragma unroll
    for (int m = 0; m < 4; ++m) {
      const float base = dsc[m] - soff;
      short8 af;
      #pragma unroll
      for (int t = 0; t < 8; ++t) {
        const float u = fmaf(-STEP, (float)t, base);
        af[t] = (short)f2bf(fexp2(-u*u));
      }
      #pragma unroll
      for (int nt = 0; nt < 4; ++nt)
        acc[m][nt] = __builtin_amdgcn_mfma_f32_16x16x32_bf16(af, bfr[s][nt], acc[m][nt], 0, 0, 0);
    }
  }

  __syncthreads();   // b2: G1l/G2l/kfl visible

  // proj B-fragments (load under the gate-phase latency)
  short8 wb[2];
  #pragma unroll
  for (int s = 0; s < 2; ++s)
    wb[s] = *(const short8*)&woF[(s*256 + p)*8];

  // ---- gate * (DB + b_db) * kf, reduce over i --------------------------
  // C frag: i = 4*q+r, j = 4*w+m, h = 16*nt+c
  float g1v[4][4], kfv[4][4];
  #pragma unroll
  for (int nt = 0; nt < 4; ++nt)
    #pragma unroll
    for (int r = 0; r < 4; ++r) {
      g1v[nt][r] = G1l[4*q + r][16*nt + c];
      kfv[nt][r] = kfl[4*q + r][16*nt + c];
    }

  float upd[4][4];
  #pragma unroll
  for (int m = 0; m < 4; ++m) {
    #pragma unroll
    for (int nt = 0; nt < 4; ++nt) {
      const float g2vm = G2l[4*w + m][16*nt + c];
      float ss = 0.f;
      #pragma unroll
      for (int r = 0; r < 4; ++r) {
        const float gate = __builtin_amdgcn_rcpf(1.0f + fexp2(-(g1v[nt][r] + g2vm)));
        ss = fmaf(gate * (acc[m][nt][r] + bdb[nt]), kfv[nt][r], ss);
      }
      ss += __shfl_xor(ss, 16);
      ss += __shfl_xor(ss, 32);
      upd[m][nt] = ss;
    }
  }

  // ---- in-register LayerNorm (rows j = 4w+m are wave-local) ------------
  #pragma unroll
  for (int m = 0; m < 4; ++m) {
    float s1 = (upd[m][0] + upd[m][1]) + (upd[m][2] + upd[m][3]);
    float s2 = fmaf(upd[m][0], upd[m][0],
               fmaf(upd[m][1], upd[m][1],
               fmaf(upd[m][2], upd[m][2], upd[m][3]*upd[m][3])));
    #pragma unroll
    for (int mk = 1; mk <= 8; mk <<= 1) {
      s1 += __shfl_xor(s1, mk);
      s2 += __shfl_xor(s2, mk);
    }
    const float mean = s1 * 0.015625f;
    const float var  = fmaf(s2, 0.015625f, -mean*mean);
    const float rstd = rsqrtf(var + 1e-5f);
    #pragma unroll
    for (int nt = 0; nt < 4; ++nt)
      if (nt == q)
        xh[4*w + m][16*q + c] = f2bf((upd[m][nt] - mean) * rstd);
  }
  __syncthreads();   // b3: xh visible

  // ---- MFMA2: out = xhat @ (ln_g*w_out) + bias2 ------------------------
  f32x4 acc2 = {};
  #pragma unroll
  for (int s = 0; s < 2; ++s) {
    const short8 af = *(const short8*)&xh[c][q*8 + 32*s];
    acc2 = __builtin_amdgcn_mfma_f32_16x16x32_bf16(af, wb[s], acc2, 0, 0, 0);
  }
  #pragma unroll
  for (int r = 0; r < 4; ++r)
    out[(n*KNB + 4*q + r)*CZ + 16*w + c] = acc2[r] + bo;
}

extern "C" void kernel_launch(void* const* d_in, const int* in_sizes, int n_in,
                              void* d_out, int out_size, void* d_ws, size_t ws_size,
                              hipStream_t stream)
{
  const float* nf     = (const float*)d_in[0];
  const float* trans  = (const float*)d_in[1];
  const float* ef     = (const float*)d_in[2];
  const int*   eidx   = (const int*)d_in[3];
  const float* w_gate = (const float*)d_in[4];
  const float* b_gate = (const float*)d_in[5];
  const float* w_db   = (const float*)d_in[6];
  const float* b_db   = (const float*)d_in[7];
  const float* w_edge = (const float*)d_in[8];
  const float* b_edge = (const float*)d_in[9];
  const float* ln_g   = (const float*)d_in[10];
  const float* ln_b   = (const float*)d_in[11];
  const float* w_out  = (const float*)d_in[12];
  const float* b_out  = (const float*)d_in[13];
  float* out = (float*)d_out;

  float* g1    = (float*)d_ws;           // [2000][64]
  float* g2    = g1 + NND*CZ;            // [2000][64]
  float* bias2 = g2 + NND*CZ;            // [64]
  unsigned short* wdbF = (unsigned short*)(bias2 + CZ);  // 4096 bf16, 16B-aligned
  unsigned short* wedF = wdbF + 4096;
  unsigned short* woF  = wedF + 4096;

  precompute_kernel<<<NND/4 + 1, 256, 0, stream>>>(
      nf, w_gate, b_gate, ln_b, w_out, b_out, w_db, w_edge, ln_g,
      g1, g2, bias2, wdbF, wedF, woF);
  fused_main_kernel<<<NND, 256, 0, stream>>>(
      trans, eidx, g1, g2, ef, b_edge, b_db, bias2,
      wdbF, wedF, woF, out);
}

// Round 5
// 33.989 us; speedup vs baseline: 4.2124x; 1.0644x over previous
//
#include <hip/hip_runtime.h>

#define NND 2000
#define KNB 16
#define CS 128
#define CZ 64
#define NE (NND*KNB)

typedef __attribute__((ext_vector_type(8))) short short8;
typedef __attribute__((ext_vector_type(4))) float f32x4;
typedef __attribute__((ext_vector_type(2))) unsigned int uint2v;

__device__ __forceinline__ unsigned short f2bf(float f) {
  unsigned int u = __float_as_uint(f);
  u += 0x7fffu + ((u >> 16) & 1u);      // RNE round to bf16
  return (unsigned short)(u >> 16);
}

__device__ __forceinline__ float fexp2(float x) {
#if __has_builtin(__builtin_amdgcn_exp2f)
  return __builtin_amdgcn_exp2f(x);
#else
  return __expf(0.6931471805599453f * x);
#endif
}

// ---------------------------------------------------------------------------
// Precompute:
//   blocks [0,500): per-node gate logits G1/G2 (b_gate in G1, log2e folded),
//                   4-way ILP to break the 128-deep dependent FMA chain.
//   block 500: wave0 bias2; wave1 wdbF; wave2 wedF; wave3 woF  (bf16 frags)
// ---------------------------------------------------------------------------
__global__ __launch_bounds__(256) void precompute_kernel(
    const float* __restrict__ nf,
    const float* __restrict__ w_gate, const float* __restrict__ b_gate,
    const float* __restrict__ ln_b, const float* __restrict__ w_out,
    const float* __restrict__ b_out,
    const float* __restrict__ w_db, const float* __restrict__ w_edge,
    const float* __restrict__ ln_g,
    float* __restrict__ g1, float* __restrict__ g2, float* __restrict__ bias2,
    unsigned short* __restrict__ wdbF, unsigned short* __restrict__ wedF,
    unsigned short* __restrict__ woF)
{
  const int lane = threadIdx.x & 63;
  const int wv   = threadIdx.x >> 6;
  const int b    = blockIdx.x;
  if (b < NND/4) {
    const int v = b*4 + wv;
    const float* nrow = nf + v*CS;
    float a10=0.f,a11=0.f,a12=0.f,a13=0.f;
    float a20=0.f,a21=0.f,a22=0.f,a23=0.f;
    #pragma unroll
    for (int cc = 0; cc < CS; cc += 4) {
      const f32x4 x = *(const f32x4*)&nrow[cc];
      a10 = fmaf(x[0], w_gate[(cc+0)*CZ + lane], a10);
      a11 = fmaf(x[1], w_gate[(cc+1)*CZ + lane], a11);
      a12 = fmaf(x[2], w_gate[(cc+2)*CZ + lane], a12);
      a13 = fmaf(x[3], w_gate[(cc+3)*CZ + lane], a13);
      a20 = fmaf(x[0], w_gate[(CS+cc+0)*CZ + lane], a20);
      a21 = fmaf(x[1], w_gate[(CS+cc+1)*CZ + lane], a21);
      a22 = fmaf(x[2], w_gate[(CS+cc+2)*CZ + lane], a22);
      a23 = fmaf(x[3], w_gate[(CS+cc+3)*CZ + lane], a23);
    }
    const float a1 = b_gate[lane] + ((a10+a11)+(a12+a13));
    const float a2 = (a20+a21)+(a22+a23);
    g1[v*CZ + lane] = a1 * 1.4426950408889634f;   // log2e folded (exp2 gate)
    g2[v*CZ + lane] = a2 * 1.4426950408889634f;
  } else if (wv == 0) {
    float a = b_out[lane];
    #pragma unroll
    for (int cc = 0; cc < CZ; ++cc)
      a = fmaf(ln_b[cc], w_out[cc*CZ + lane], a);
    bias2[lane] = a;
  } else if (wv == 1) {
    for (int e = lane; e < 4096; e += 64) {
      const int entry = e >> 3, t = e & 7;
      const int l2 = entry & 63, sn = entry >> 6;
      const int s = sn >> 2, nt = sn & 3;
      const int q = l2 >> 4, c = l2 & 15;
      const int k = 32*s + 8*q + t, h = 16*nt + c;
      wdbF[e] = f2bf(w_db[k*CZ + h]);
    }
  } else if (wv == 2) {
    for (int e = lane; e < 4096; e += 64) {
      const int entry = e >> 3, t = e & 7;
      const int p2 = entry & 255, s = entry >> 8;
      const int q = (p2 >> 4) & 3, c = p2 & 15;
      const int col = 16*(p2 >> 6) + c, k = 32*s + 8*q + t;
      wedF[e] = f2bf(w_edge[k*CZ + col]);
    }
  } else {
    for (int e = lane; e < 4096; e += 64) {
      const int entry = e >> 3, t = e & 7;
      const int p2 = entry & 255, s = entry >> 8;
      const int q = (p2 >> 4) & 3, c = p2 & 15;
      const int col = 16*(p2 >> 6) + c, k = 32*s + 8*q + t;
      woF[e] = f2bf(w_out[k*CZ + col] * ln_g[k]);
    }
  }
}

// ---------------------------------------------------------------------------
// Fused main kernel: one block (4 waves) per node. 3 barriers.
// All global latency front-loaded before b1 (register-direct gathers, no
// LDS intermediaries). bfr streamed per-nt to stay under 128 VGPRs.
// ---------------------------------------------------------------------------
__global__ __launch_bounds__(256, 4) void fused_main_kernel(
    const float* __restrict__ trans, const int* __restrict__ eidx,
    const float* __restrict__ g1, const float* __restrict__ g2,
    const float* __restrict__ ef, const float* __restrict__ b_edge,
    const float* __restrict__ b_db, const float* __restrict__ bias2,
    const unsigned short* __restrict__ wdbF,
    const unsigned short* __restrict__ wedF,
    const unsigned short* __restrict__ woF,
    float* __restrict__ out)
{
  __shared__ unsigned short efl[KNB][72];    // ef tile bf16
  __shared__ float G1l[KNB][68];
  __shared__ float G2l[KNB][68];
  __shared__ float kfl[KNB][68];
  __shared__ unsigned short xh[KNB][72];     // xhat bf16

  const int n = blockIdx.x;
  const int p = threadIdx.x;
  const int w = p >> 6;
  const int l = p & 63;
  const int q = l >> 4;
  const int c = l & 15;
  const int r16 = p >> 4, c4 = (p & 15) * 4;

  // ---- front-loaded global traffic (all independent of LDS/barriers) ----
  const int sr = eidx[n*KNB + r16];          // G-row gather index
  const int sc = eidx[n*KNB + c];            // t_i index
  int sj[4];
  #pragma unroll
  for (int m = 0; m < 4; ++m) sj[m] = eidx[n*KNB + 4*w + m];

  const f32x4 g1row = *(const f32x4*)&g1[sr*CZ + c4];
  const f32x4 g2row = *(const f32x4*)&g2[sr*CZ + c4];
  const f32x4 efrow = *(const f32x4*)&ef[(n*KNB + r16)*CZ + c4];

  const float tc0 = trans[sc*3+0], tc1 = trans[sc*3+1], tc2 = trans[sc*3+2];
  float tj[4][3];
  #pragma unroll
  for (int m = 0; m < 4; ++m) {
    tj[m][0] = trans[sj[m]*3+0];
    tj[m][1] = trans[sj[m]*3+1];
    tj[m][2] = trans[sj[m]*3+2];
  }

  short8 wed[2];
  #pragma unroll
  for (int s = 0; s < 2; ++s)
    wed[s] = *(const short8*)&wedF[(s*256 + p)*8];
  short8 bcur[2];
  #pragma unroll
  for (int s = 0; s < 2; ++s)
    bcur[s] = *(const short8*)&wdbF[((s*4 + 0)*64 + l)*8];

  const float be = b_edge[16*w + c];
  const float bo = bias2[16*w + c];
  float bdb[4];
  #pragma unroll
  for (int nt = 0; nt < 4; ++nt) bdb[nt] = b_db[16*nt + c];

  // ---- register-only compute while loads land ----
  // pair (i=c, j=4w+m); dist pre-scaled so rbf = exp2(-u^2)
  const float STEP = 1.2201878439258035f;
  float dsc[4];
  #pragma unroll
  for (int m = 0; m < 4; ++m) {
    const float dx = tc0 - tj[m][0] + 1e-8f;
    const float dy = tc1 - tj[m][1] + 1e-8f;
    const float dz = tc2 - tj[m][2] + 1e-8f;
    dsc[m] = sqrtf(fmaf(dx,dx, fmaf(dy,dy, dz*dz))) * 3.8435917081166394f;
  }
  const float qoff = (float)(8*q) * STEP;

  // rbf A-frags: af[s][m], row i=c, k = 32s+8q+t   (64 exp2)
  short8 af[2][4];
  #pragma unroll
  for (int s = 0; s < 2; ++s) {
    const float soff = qoff + (float)(32*s) * STEP;
    #pragma unroll
    for (int m = 0; m < 4; ++m) {
      const float base = dsc[m] - soff;
      short8 v;
      #pragma unroll
      for (int t = 0; t < 8; ++t) {
        const float u = fmaf(-STEP, (float)t, base);
        v[t] = (short)f2bf(fexp2(-u*u));
      }
      af[s][m] = v;
    }
  }

  { // stage ef tile bf16 + G rows (register -> LDS)
    uint2v pk;
    pk[0] = (unsigned int)f2bf(efrow[0]) | ((unsigned int)f2bf(efrow[1]) << 16);
    pk[1] = (unsigned int)f2bf(efrow[2]) | ((unsigned int)f2bf(efrow[3]) << 16);
    *(uint2v*)&efl[r16][c4] = pk;
    *(f32x4*)&G1l[r16][c4] = g1row;
    *(f32x4*)&G2l[r16][c4] = g2row;
  }
  __syncthreads();   // b1: efl, G1l, G2l visible

  { // MFMA0: kf tile; wave w owns cols 16w..16w+15
    f32x4 ak = {};
    #pragma unroll
    for (int s = 0; s < 2; ++s) {
      const short8 a0 = *(const short8*)&efl[c][q*8 + 32*s];
      ak = __builtin_amdgcn_mfma_f32_16x16x32_bf16(a0, wed[s], ak, 0, 0, 0);
    }
    #pragma unroll
    for (int r = 0; r < 4; ++r)
      kfl[4*q + r][16*w + c] = ak[r] + be;
  }
  __syncthreads();   // b2: kfl visible

  // ---- per-nt fused MFMA1 + gate + i-reduce (acc streamed, 16 regs) ----
  float upd[4][4];   // [m][nt]
  #pragma unroll
  for (int nt = 0; nt < 4; ++nt) {
    short8 bnext[2];
    if (nt < 3) {
      #pragma unroll
      for (int s = 0; s < 2; ++s)
        bnext[s] = *(const short8*)&wdbF[((s*4 + nt+1)*64 + l)*8];
    }
    f32x4 acc[4] = {};
    #pragma unroll
    for (int s = 0; s < 2; ++s)
      #pragma unroll
      for (int m = 0; m < 4; ++m)
        acc[m] = __builtin_amdgcn_mfma_f32_16x16x32_bf16(af[s][m], bcur[s], acc[m], 0, 0, 0);

    float g1v[4], kfv[4];
    #pragma unroll
    for (int r = 0; r < 4; ++r) {
      g1v[r] = G1l[4*q + r][16*nt + c];
      kfv[r] = kfl[4*q + r][16*nt + c];
    }
    const float bdbn = bdb[nt];
    #pragma unroll
    for (int m = 0; m < 4; ++m) {
      const float g2vm = G2l[4*w + m][16*nt + c];
      float ss = 0.f;
      #pragma unroll
      for (int r = 0; r < 4; ++r) {
        const float gate = __builtin_amdgcn_rcpf(1.0f + fexp2(-(g1v[r] + g2vm)));
        ss = fmaf(gate * (acc[m][r] + bdbn), kfv[r], ss);
      }
      ss += __shfl_xor(ss, 16);
      ss += __shfl_xor(ss, 32);
      upd[m][nt] = ss;
    }
    if (nt < 3) { bcur[0] = bnext[0]; bcur[1] = bnext[1]; }
  }

  // proj B-frags (hide under LN)
  short8 wb[2];
  #pragma unroll
  for (int s = 0; s < 2; ++s)
    wb[s] = *(const short8*)&woF[(s*256 + p)*8];

  // ---- LayerNorm: q-group q owns row j = 4w+q (no redundancy) ----------
  {
    float v[4];
    #pragma unroll
    for (int nt = 0; nt < 4; ++nt)
      v[nt] = (q == 0) ? upd[0][nt] : (q == 1) ? upd[1][nt]
            : (q == 2) ? upd[2][nt] : upd[3][nt];
    float s1 = (v[0] + v[1]) + (v[2] + v[3]);
    float s2 = fmaf(v[0],v[0], fmaf(v[1],v[1], fmaf(v[2],v[2], v[3]*v[3])));
    #pragma unroll
    for (int mk = 1; mk <= 8; mk <<= 1) {
      s1 += __shfl_xor(s1, mk);
      s2 += __shfl_xor(s2, mk);
    }
    const float mean = s1 * 0.015625f;
    const float var  = fmaf(s2, 0.015625f, -mean*mean);
    const float rstd = rsqrtf(var + 1e-5f);
    #pragma unroll
    for (int nt = 0; nt < 4; ++nt)
      xh[4*w + q][16*nt + c] = f2bf((v[nt] - mean) * rstd);
  }
  __syncthreads();   // b3: xh visible

  // ---- MFMA2: out = xhat @ (ln_g*w_out) + bias2 ------------------------
  f32x4 acc2 = {};
  #pragma unroll
  for (int s = 0; s < 2; ++s) {
    const short8 a2f = *(const short8*)&xh[c][q*8 + 32*s];
    acc2 = __builtin_amdgcn_mfma_f32_16x16x32_bf16(a2f, wb[s], acc2, 0, 0, 0);
  }
  #pragma unroll
  for (int r = 0; r < 4; ++r)
    out[(n*KNB + 4*q + r)*CZ + 16*w + c] = acc2[r] + bo;
}

extern "C" void kernel_launch(void* const* d_in, const int* in_sizes, int n_in,
                              void* d_out, int out_size, void* d_ws, size_t ws_size,
                              hipStream_t stream)
{
  const float* nf     = (const float*)d_in[0];
  const float* trans  = (const float*)d_in[1];
  const float* ef     = (const float*)d_in[2];
  const int*   eidx   = (const int*)d_in[3];
  const float* w_gate = (const float*)d_in[4];
  const float* b_gate = (const float*)d_in[5];
  const float* w_db   = (const float*)d_in[6];
  const float* b_db   = (const float*)d_in[7];
  const float* w_edge = (const float*)d_in[8];
  const float* b_edge = (const float*)d_in[9];
  const float* ln_g   = (const float*)d_in[10];
  const float* ln_b   = (const float*)d_in[11];
  const float* w_out  = (const float*)d_in[12];
  const float* b_out  = (const float*)d_in[13];
  float* out = (float*)d_out;

  float* g1    = (float*)d_ws;           // [2000][64]
  float* g2    = g1 + NND*CZ;            // [2000][64]
  float* bias2 = g2 + NND*CZ;            // [64]
  unsigned short* wdbF = (unsigned short*)(bias2 + CZ);
  unsigned short* wedF = wdbF + 4096;
  unsigned short* woF  = wedF + 4096;

  precompute_kernel<<<NND/4 + 1, 256, 0, stream>>>(
      nf, w_gate, b_gate, ln_b, w_out, b_out, w_db, w_edge, ln_g,
      g1, g2, bias2, wdbF, wedF, woF);
  fused_main_kernel<<<NND, 256, 0, stream>>>(
      trans, eidx, g1, g2, ef, b_edge, b_db, bias2,
      wdbF, wedF, woF, out);
}